// Round 2
// baseline (81.741 us; speedup 1.0000x reference)
//
#include <hip/hip_runtime.h>

// UnionLayer: out[b, n]      = -1/(-1 + sum_d ln(1 - (1-x[b,d])*W_con[n,d]))   n in [0,256)
//             out[b, 256+n]  = 1 - (-1/(-1 + sum_d ln(1 - x[b,d]*W_dis[n,d])))
// B=1024, D=512, N=256 -> out (1024, 512) f32.
//
// sum(log) -> log(product) in 64-term chunks: terms strictly > 0.5 (w < 0.5),
// so chunk product >= 2^-64 — provably no underflow. Inner loop = fma+mul only.
//
// K-split by 8 for occupancy: grid (8 n, 16 b, 8 k) = 1024 blocks = 4/CU =
// 16 waves/CU. Each block computes partial log2-sums over 64 d's into its own
// ws slice (atomic-free); pass2 sums 8 slices + final transform.

#define DDIM 512
#define NTOT 512
#define NHALF 256
#define BM 64
#define BN 64
#define BK 64
#define KS 8
#define P  68                 // LDS row stride (floats): 68%32=4 -> conflict-free-ish
#define SLICE (1024 * 512)    // 524288 floats per k-slice

__global__ __launch_bounds__(256) void union_pass1(
    const float* __restrict__ x,
    const float* __restrict__ Wc,
    const float* __restrict__ Wd,
    float* __restrict__ ws)
{
    __shared__ float xs[BM * P];
    __shared__ float wsh[BN * P];

    const int tid = threadIdx.x;
    const int n0  = blockIdx.x * BN;
    const int b0  = blockIdx.y * BM;
    const int d0  = blockIdx.z * BK;
    const bool isCon = (n0 < NHALF);
    const float csel = isCon ? -1.0f : 1.0f;   // u = csel*x + coff
    const float coff = isCon ?  1.0f : 0.0f;
    const float* Wb = isCon ? (Wc + n0 * DDIM) : (Wd + (n0 - NHALF) * DDIM);

    // stage both 64x64 tiles: 1024 float4 each, 4 per thread, fully coalesced
#pragma unroll
    for (int i = 0; i < 4; ++i) {
        const int f   = i * 256 + tid;   // 0..1023
        const int row = f >> 4;          // 16 float4 per row
        const int c4  = (f & 15) * 4;
        float4 xv = *reinterpret_cast<const float4*>(&x[(b0 + row) * DDIM + d0 + c4]);
        float4 u;
        u.x = fmaf(csel, xv.x, coff);
        u.y = fmaf(csel, xv.y, coff);
        u.z = fmaf(csel, xv.z, coff);
        u.w = fmaf(csel, xv.w, coff);
        *reinterpret_cast<float4*>(&xs[row * P + c4]) = u;
        float4 wv = *reinterpret_cast<const float4*>(&Wb[row * DDIM + d0 + c4]);
        *reinterpret_cast<float4*>(&wsh[row * P + c4]) = wv;
    }
    __syncthreads();

    // compute map: 16x16 threads, each 4x4 outputs, interleaved by 16
    const int tb = tid >> 4;   // 0..15
    const int tn = tid & 15;   // 0..15

    float prod[4][4];
#pragma unroll
    for (int i = 0; i < 4; ++i)
#pragma unroll
        for (int j = 0; j < 4; ++j) prod[i][j] = 1.0f;

#pragma unroll 4
    for (int k4 = 0; k4 < 16; ++k4) {
        const int kk = k4 * 4;
        float4 uu[4], wv[4];
#pragma unroll
        for (int i = 0; i < 4; ++i)
            uu[i] = *reinterpret_cast<const float4*>(&xs[(tb + 16 * i) * P + kk]);
#pragma unroll
        for (int j = 0; j < 4; ++j)
            wv[j] = *reinterpret_cast<const float4*>(&wsh[(tn + 16 * j) * P + kk]);
#pragma unroll
        for (int i = 0; i < 4; ++i)
#pragma unroll
            for (int j = 0; j < 4; ++j) {
                prod[i][j] *= fmaf(-uu[i].x, wv[j].x, 1.0f);
                prod[i][j] *= fmaf(-uu[i].y, wv[j].y, 1.0f);
                prod[i][j] *= fmaf(-uu[i].z, wv[j].z, 1.0f);
                prod[i][j] *= fmaf(-uu[i].w, wv[j].w, 1.0f);
            }
    }

    // one log2 per output for this 64-d chunk; store partial to own slice
    float* dst = ws + (size_t)blockIdx.z * SLICE;
#pragma unroll
    for (int i = 0; i < 4; ++i)
#pragma unroll
        for (int j = 0; j < 4; ++j)
            dst[(b0 + tb + 16 * i) * NTOT + (n0 + tn + 16 * j)] = __log2f(prod[i][j]);
}

__global__ __launch_bounds__(256) void union_pass2(
    const float* __restrict__ ws, float* __restrict__ out)
{
    const int i = blockIdx.x * 256 + threadIdx.x;   // float4 index, 131072 total
    const float4* w4 = reinterpret_cast<const float4*>(ws);
    float4 s = w4[i];
#pragma unroll
    for (int k = 1; k < KS; ++k) {
        const float4 t = w4[(size_t)k * (SLICE / 4) + i];
        s.x += t.x; s.y += t.y; s.z += t.z; s.w += t.w;
    }
    constexpr float LN2 = 0.69314718055994530942f;
    const int col = (i * 4) & (NTOT - 1);
    const bool con = col < NHALF;   // float4 never straddles the 256 boundary
    float4 o;
    o.x = 1.0f / (1.0f - s.x * LN2);
    o.y = 1.0f / (1.0f - s.y * LN2);
    o.z = 1.0f / (1.0f - s.z * LN2);
    o.w = 1.0f / (1.0f - s.w * LN2);
    if (!con) {
        o.x = 1.0f - o.x; o.y = 1.0f - o.y; o.z = 1.0f - o.z; o.w = 1.0f - o.w;
    }
    reinterpret_cast<float4*>(out)[i] = o;
}

extern "C" void kernel_launch(void* const* d_in, const int* in_sizes, int n_in,
                              void* d_out, int out_size, void* d_ws, size_t ws_size,
                              hipStream_t stream) {
    const float* x  = (const float*)d_in[0];
    const float* Wc = (const float*)d_in[1];
    const float* Wd = (const float*)d_in[2];
    float* out = (float*)d_out;
    float* ws  = (float*)d_ws;   // needs KS*2MB = 16 MB

    dim3 g1(NTOT / BN, 1024 / BM, KS);   // (8, 16, 8)
    union_pass1<<<g1, 256, 0, stream>>>(x, Wc, Wd, ws);
    union_pass2<<<(SLICE / 4) / 256, 256, 0, stream>>>(ws, out);
}

// Round 3
// 79.773 us; speedup vs baseline: 1.0247x; 1.0247x over previous
//
#include <hip/hip_runtime.h>

// UnionLayer: out[b, n]      = -1/(-1 + sum_d ln(1 - (1-x[b,d])*W_con[n,d]))   n in [0,256)
//             out[b, 256+n]  = 1 - (-1/(-1 + sum_d ln(1 - x[b,d]*W_dis[n,d])))
// B=1024, D=512, N=256 -> out (1024, 512) f32.
//
// sum(log) -> log(product) in 32-term chunks: each term in (0.5, 1] (w < 0.5),
// so chunk product >= 2^-32 — no underflow. Inner loop = fma+mul only.
//
// Occupancy-max variant: BK=32, KS=16 -> 2048 blocks, 18 KB LDS/block ->
// 8 blocks/CU = 32 waves/CU (hardware max). Atomic-free K-split partials in
// ws slices; pass2 sums 16 slices + applies the final transform.

#define DDIM 512
#define NTOT 512
#define NHALF 256
#define BM 64
#define BN 64
#define BK 32
#define KS 16
#define P  36                 // LDS row stride (floats); 36 % 32 = 4 -> <=2-way
#define SLICE (1024 * 512)    // floats per k-slice

__global__ __launch_bounds__(256) void union_pass1(
    const float* __restrict__ x,
    const float* __restrict__ Wc,
    const float* __restrict__ Wd,
    float* __restrict__ ws)
{
    __shared__ float xs[BM * P];
    __shared__ float wsh[BN * P];

    const int tid = threadIdx.x;
    const int n0  = blockIdx.x * BN;
    const int b0  = blockIdx.y * BM;
    const int d0  = blockIdx.z * BK;
    const bool isCon = (n0 < NHALF);
    const float csel = isCon ? -1.0f : 1.0f;   // u = csel*x + coff
    const float coff = isCon ?  1.0f : 0.0f;
    const float* Wb = isCon ? (Wc + n0 * DDIM) : (Wd + (n0 - NHALF) * DDIM);

    // stage 64x32 x-tile and 64x32 W-tile: 512 float4 each, 2 per thread
#pragma unroll
    for (int i = 0; i < 2; ++i) {
        const int f   = i * 256 + tid;   // 0..511
        const int row = f >> 3;          // 8 float4 per row
        const int c4  = (f & 7) * 4;
        float4 xv = *reinterpret_cast<const float4*>(&x[(b0 + row) * DDIM + d0 + c4]);
        float4 u;
        u.x = fmaf(csel, xv.x, coff);
        u.y = fmaf(csel, xv.y, coff);
        u.z = fmaf(csel, xv.z, coff);
        u.w = fmaf(csel, xv.w, coff);
        *reinterpret_cast<float4*>(&xs[row * P + c4]) = u;
        float4 wv = *reinterpret_cast<const float4*>(&Wb[row * DDIM + d0 + c4]);
        *reinterpret_cast<float4*>(&wsh[row * P + c4]) = wv;
    }
    __syncthreads();

    // compute map: 16x16 threads, each 4x4 outputs, interleaved by 16
    const int tb = tid >> 4;   // 0..15
    const int tn = tid & 15;   // 0..15

    float prod[4][4];
#pragma unroll
    for (int i = 0; i < 4; ++i)
#pragma unroll
        for (int j = 0; j < 4; ++j) prod[i][j] = 1.0f;

#pragma unroll
    for (int k4 = 0; k4 < 8; ++k4) {
        const int kk = k4 * 4;
        float4 uu[4], wv[4];
#pragma unroll
        for (int i = 0; i < 4; ++i)
            uu[i] = *reinterpret_cast<const float4*>(&xs[(tb + 16 * i) * P + kk]);
#pragma unroll
        for (int j = 0; j < 4; ++j)
            wv[j] = *reinterpret_cast<const float4*>(&wsh[(tn + 16 * j) * P + kk]);
#pragma unroll
        for (int i = 0; i < 4; ++i)
#pragma unroll
            for (int j = 0; j < 4; ++j) {
                prod[i][j] *= fmaf(-uu[i].x, wv[j].x, 1.0f);
                prod[i][j] *= fmaf(-uu[i].y, wv[j].y, 1.0f);
                prod[i][j] *= fmaf(-uu[i].z, wv[j].z, 1.0f);
                prod[i][j] *= fmaf(-uu[i].w, wv[j].w, 1.0f);
            }
    }

    // one log2 per output for this 32-d chunk; store partial to own slice
    float* dst = ws + (size_t)blockIdx.z * SLICE;
#pragma unroll
    for (int i = 0; i < 4; ++i)
#pragma unroll
        for (int j = 0; j < 4; ++j)
            dst[(b0 + tb + 16 * i) * NTOT + (n0 + tn + 16 * j)] = __log2f(prod[i][j]);
}

__global__ __launch_bounds__(256) void union_pass2(
    const float* __restrict__ ws, float* __restrict__ out)
{
    const int i = blockIdx.x * 256 + threadIdx.x;   // float4 index, 131072 total
    const float4* w4 = reinterpret_cast<const float4*>(ws);
    float4 s = w4[i];
#pragma unroll
    for (int k = 1; k < KS; ++k) {
        const float4 t = w4[(size_t)k * (SLICE / 4) + i];
        s.x += t.x; s.y += t.y; s.z += t.z; s.w += t.w;
    }
    constexpr float LN2 = 0.69314718055994530942f;
    const int col = (i * 4) & (NTOT - 1);
    const bool con = col < NHALF;   // float4 never straddles the 256 boundary
    float4 o;
    o.x = 1.0f / (1.0f - s.x * LN2);
    o.y = 1.0f / (1.0f - s.y * LN2);
    o.z = 1.0f / (1.0f - s.z * LN2);
    o.w = 1.0f / (1.0f - s.w * LN2);
    if (!con) {
        o.x = 1.0f - o.x; o.y = 1.0f - o.y; o.z = 1.0f - o.z; o.w = 1.0f - o.w;
    }
    reinterpret_cast<float4*>(out)[i] = o;
}

extern "C" void kernel_launch(void* const* d_in, const int* in_sizes, int n_in,
                              void* d_out, int out_size, void* d_ws, size_t ws_size,
                              hipStream_t stream) {
    const float* x  = (const float*)d_in[0];
    const float* Wc = (const float*)d_in[1];
    const float* Wd = (const float*)d_in[2];
    float* out = (float*)d_out;
    float* ws  = (float*)d_ws;   // uses KS*2MB = 32 MB of the 256 MB scratch

    dim3 g1(NTOT / BN, 1024 / BM, KS);   // (8, 16, 16) = 2048 blocks
    union_pass1<<<g1, 256, 0, stream>>>(x, Wc, Wd, ws);
    union_pass2<<<(SLICE / 4) / 256, 256, 0, stream>>>(ws, out);
}